// Round 8
// baseline (107.241 us; speedup 1.0000x reference)
//
#include <hip/hip_runtime.h>

// CapsuleConv2d fused, MI355X gfx950. ALL I/O FP32.
// B=2, C_in=128 (G=8 x M=16), 32x32, 3x3 pad 1, O=16, L=16 -> C_out=256.
// k-means (dot) routing 3 iters + squash.
//
// v5: 1 block/pixel. Priors are computed in TWO g-halves woven into the
// two-chunk LDS transpose, so u[72] is NEVER materialized in registers
// (R7 root cause: u[72]+ut2[80] simultaneously live -> ~190 regs -> scratch).
// Pass A: g=0..3 (first 64 floats of each patch row) -> LDS rows 0..35 ->
// read into ut2. Pass B: g=4..7 (second 64 floats) -> LDS rows 36..71.
// Phase 2 (thread=(o,nc)): thread owns 4-5 u-rows (all 16 l) in regs;
// routing register-local (5 exps/lane/iter), v-updates via DPP 16-lane
// all-reduce. Peak regs ~130 -> __launch_bounds__(256,3) (170 budget).

typedef float v2f __attribute__((ext_vector_type(2)));

#define NPRI 72
#define XT_ELEMS (2 * 32 * 32 * 128)   // 1 MB
#define WT_ELEMS (9 * 256 * 16)        // 576 KB
#define ROWSTR 268                     // LDS row stride (floats); 16B-aligned,
                                       // row-to-row bank shift 12 (268%32)

#define DPP_ADD(a, ctrl)                                                     \
  a += __int_as_float(__builtin_amdgcn_update_dpp(                           \
          0, __float_as_int(a), ctrl, 0xF, 0xF, true))

__device__ __forceinline__ float dpp_add16(float x) {
    // sum across each aligned 16-lane group, broadcast to all 16 lanes.
    float s = x;
    DPP_ADD(s, 0x128); DPP_ADD(s, 0x124); DPP_ADD(s, 0x122); DPP_ADD(s, 0x121);
    return s;
}

__device__ __forceinline__ float frcp(float x) {
    return __builtin_amdgcn_rcpf(x);
}

__device__ __forceinline__ v2f pkfma(v2f a, v2f b, v2f c) {
    return __builtin_elementwise_fma(a, b, c);
}

// ---- prep: blocks [0,64) x-transpose, [64,208) weight transpose ----
// xT[b][h][w][c] = x[b][c][h][w];  Wt[(ij*256+t)*16+m] = W[(t*16+m)*9+ij]
__global__ __launch_bounds__(256)
void prep_kernel(const float* __restrict__ x, const float* __restrict__ W,
                 float* __restrict__ xT, float* __restrict__ Wt) {
    const int blk = blockIdx.x;
    const int tid = threadIdx.x;
    if (blk < 64) {
        __shared__ float xs[128 * 33];
        const int b = blk >> 5, h = blk & 31;
        const float* xb = x + b * (128 * 32 * 32) + h * 32;  // [c*1024 + w]
        #pragma unroll
        for (int k = 0; k < 16; ++k) {
            int idx = k * 256 + tid;
            int c = idx >> 5, w = idx & 31;
            xs[c * 33 + w] = xb[c * 1024 + w];   // coalesced read
        }
        __syncthreads();
        float* xo = xT + (b * 32 + h) * 32 * 128;
        #pragma unroll
        for (int k = 0; k < 16; ++k) {
            int idx = k * 256 + tid;
            int w = idx >> 7, c = idx & 127;
            xo[w * 128 + c] = xs[c * 33 + w];    // coalesced write, cf-free read
        }
    } else {
        int idx = (blk - 64) * 256 + tid;        // 0..36863
        int ij = idx >> 12;
        int r  = idx & 4095;
        int tt = r >> 4;
        int m  = r & 15;
        Wt[idx] = W[(tt * 16 + m) * 9 + ij];
    }
}

// ---- main kernel v5 ----
__global__ __launch_bounds__(256, 3)
void capsule_v5(const float* __restrict__ xT, const float* __restrict__ Wt,
                float* __restrict__ out) {
    __shared__ float uTs[36 * ROWSTR];       // 38.6 KB, two-chunk transpose
    const int pix = blockIdx.x;              // 2048
    const int b = pix >> 10, h = (pix >> 5) & 31, w = pix & 31;
    const int t = threadIdx.x;
    const int o = t >> 4, nc = t & 15;       // phase1: l == nc

    v2f ut2[5][8];
    #pragma unroll
    for (int j2 = 0; j2 < 8; ++j2) ut2[4][j2] = (v2f){0.0f, 0.0f};
    const bool has5 = (nc < 8);

    // ================= PASS A: g=0..3 -> LDS rows 0..35 =================
    #pragma unroll
    for (int ij = 0; ij < 9; ++ij) {
        const int di = ij / 3, dj = ij % 3;
        const int hh = h + di - 1, ww = w + dj - 1;
        if ((unsigned)hh < 32u && (unsigned)ww < 32u) {     // block-uniform
            const v2f* sp2 = (const v2f*)(xT + ((b * 32 + hh) * 32 + ww) * 128);
            const v2f* wp2 = (const v2f*)(Wt + (ij * 256 + t) * 16);
            v2f wr2[8];
            #pragma unroll
            for (int m = 0; m < 8; ++m) wr2[m] = wp2[m];
            #pragma unroll
            for (int g = 0; g < 4; ++g) {
                v2f acc = {0.0f, 0.0f};
                #pragma unroll
                for (int m = 0; m < 8; ++m)
                    acc = pkfma(sp2[g * 8 + m], wr2[m], acc);   // v_pk_fma_f32
                uTs[(g * 9 + ij) * ROWSTR + t] = acc.x + acc.y;
            }
        } else {
            #pragma unroll
            for (int g = 0; g < 4; ++g)
                uTs[(g * 9 + ij) * ROWSTR + t] = 0.0f;
        }
    }
    __syncthreads();
    // read chunk A: n = nc, 16+nc, and (nc<4) 32+nc
    {
        #pragma unroll
        for (int k = 0; k < 2; ++k) {
            const v2f* r2 = (const v2f*)&uTs[(nc + 16 * k) * ROWSTR + o * 16];
            #pragma unroll
            for (int j2 = 0; j2 < 8; ++j2) ut2[k][j2] = r2[j2];
        }
        if (nc < 4) {
            const v2f* r2 = (const v2f*)&uTs[(32 + nc) * ROWSTR + o * 16];
            #pragma unroll
            for (int j2 = 0; j2 < 8; ++j2) ut2[2][j2] = r2[j2];
        }
    }
    __syncthreads();

    // ================= PASS B: g=4..7 -> LDS rows 36..71 (stored -36) ====
    #pragma unroll
    for (int ij = 0; ij < 9; ++ij) {
        const int di = ij / 3, dj = ij % 3;
        const int hh = h + di - 1, ww = w + dj - 1;
        if ((unsigned)hh < 32u && (unsigned)ww < 32u) {
            const v2f* sp2 = (const v2f*)(xT + ((b * 32 + hh) * 32 + ww) * 128);
            const v2f* wp2 = (const v2f*)(Wt + (ij * 256 + t) * 16);
            v2f wr2[8];
            #pragma unroll
            for (int m = 0; m < 8; ++m) wr2[m] = wp2[m];
            #pragma unroll
            for (int g = 0; g < 4; ++g) {
                v2f acc = {0.0f, 0.0f};
                #pragma unroll
                for (int m = 0; m < 8; ++m)
                    acc = pkfma(sp2[(g + 4) * 8 + m], wr2[m], acc);
                uTs[(g * 9 + ij) * ROWSTR + t] = acc.x + acc.y;  // row-36
            }
        } else {
            #pragma unroll
            for (int g = 0; g < 4; ++g)
                uTs[(g * 9 + ij) * ROWSTR + t] = 0.0f;
        }
    }
    __syncthreads();
    // read chunk B: n = (nc>=4) 32+nc -> row nc-4; 48+nc -> 12+nc; (nc<8) 64+nc -> 28+nc
    {
        if (nc >= 4) {
            const v2f* r2 = (const v2f*)&uTs[(nc - 4) * ROWSTR + o * 16];
            #pragma unroll
            for (int j2 = 0; j2 < 8; ++j2) ut2[2][j2] = r2[j2];
        }
        {
            const v2f* r2 = (const v2f*)&uTs[(12 + nc) * ROWSTR + o * 16];
            #pragma unroll
            for (int j2 = 0; j2 < 8; ++j2) ut2[3][j2] = r2[j2];
        }
        if (has5) {
            const v2f* r2 = (const v2f*)&uTs[(28 + nc) * ROWSTR + o * 16];
            #pragma unroll
            for (int j2 = 0; j2 < 8; ++j2) ut2[4][j2] = r2[j2];
        }
    }

    // ---- init v = mean over n (ut2[4]=0 for !has5 lanes) ----
    v2f va2[8];
    #pragma unroll
    for (int j2 = 0; j2 < 8; ++j2) {
        v2f s = (ut2[0][j2] + ut2[1][j2]) + (ut2[2][j2] + ut2[3][j2]) + ut2[4][j2];
        va2[j2].x = dpp_add16(s.x) * (1.0f / NPRI);
        va2[j2].y = dpp_add16(s.y) * (1.0f / NPRI);
    }

    // ---- 3 routing iterations, registers only ----
    #pragma unroll 1
    for (int it = 0; it < 3; ++it) {
        v2f ssv = {0.0f, 0.0f};
        #pragma unroll
        for (int j2 = 0; j2 < 8; ++j2) ssv = pkfma(va2[j2], va2[j2], ssv);
        float ss = ssv.x + ssv.y;
        float inv = frcp(fmaxf(sqrtf(ss), 1e-12f));

        float e[5], ssum = 0.0f;
        #pragma unroll
        for (int k = 0; k < 5; ++k) {
            v2f d2 = {0.0f, 0.0f};
            #pragma unroll
            for (int j2 = 0; j2 < 8; ++j2) d2 = pkfma(ut2[k][j2], va2[j2], d2);
            float ek = __expf((d2.x + d2.y) * inv);
            if (k == 4) ek = has5 ? ek : 0.0f;
            e[k] = ek;
            ssum += ek;
        }
        ssum = dpp_add16(ssum);
        float rs = frcp(ssum);

        v2f e0 = {e[0], e[0]}, e1 = {e[1], e[1]}, e2v = {e[2], e[2]};
        v2f e3 = {e[3], e[3]}, e4 = {e[4], e[4]};
        #pragma unroll
        for (int j2 = 0; j2 < 8; ++j2) {
            v2f pv = e0 * ut2[0][j2];
            pv = pkfma(e1, ut2[1][j2], pv);
            pv = pkfma(e2v, ut2[2][j2], pv);
            pv = pkfma(e3, ut2[3][j2], pv);
            pv = pkfma(e4, ut2[4][j2], pv);
            va2[j2].x = dpp_add16(pv.x) * rs;
            va2[j2].y = dpp_add16(pv.y) * rs;
        }
    }

    // ---- squash ----
    v2f ssv = {0.0f, 0.0f};
    #pragma unroll
    for (int j2 = 0; j2 < 8; ++j2) ssv = pkfma(va2[j2], va2[j2], ssv);
    float ss = ssv.x + ssv.y;
    float scale = sqrtf(ss) * frcp(1.0f + ss);

    // select component l = nc: cndmask ladder
    v2f c4[4], c2[2];
    #pragma unroll
    for (int j = 0; j < 4; ++j) c4[j] = (nc & 8) ? va2[j + 4] : va2[j];
    #pragma unroll
    for (int j = 0; j < 2; ++j) c2[j] = (nc & 4) ? c4[j + 2] : c4[j];
    v2f c1 = (nc & 2) ? c2[1] : c2[0];
    float res = ((nc & 1) ? c1.y : c1.x) * scale;

    out[((b * 256 + t) * 32 + h) * 32 + w] = res;
}

// ---- fallback (tiny ws): self-contained ----
__global__ __launch_bounds__(256, 1)
void capsule_fb(const float* __restrict__ x, const float* __restrict__ Wraw,
                float* __restrict__ out) {
    __shared__ float patch[9 * 128];
    const int blk = blockIdx.x;
    const int b = blk >> 10, h = (blk >> 5) & 31, w = blk & 31;
    const int t = threadIdx.x;

    const float* xb = x + b * (128 * 32 * 32);
    for (int idx = t; idx < 1152; idx += 256) {
        int c = idx / 9, ij = idx - c * 9;
        int di = ij / 3, dj = ij - di * 3;
        int hh = h + di - 1, ww = w + dj - 1;
        float v = 0.0f;
        if ((unsigned)hh < 32u && (unsigned)ww < 32u)
            v = xb[(c * 32 + hh) * 32 + ww];
        patch[ij * 128 + c] = v;
    }
    __syncthreads();

    float u[NPRI];
    #pragma unroll
    for (int ij = 0; ij < 9; ++ij) {
        float wr[16];
        #pragma unroll
        for (int m = 0; m < 16; ++m) wr[m] = Wraw[(t * 16 + m) * 9 + ij];
        #pragma unroll
        for (int g = 0; g < 8; ++g) {
            float acc = 0.0f;
            #pragma unroll
            for (int m = 0; m < 16; ++m)
                acc = fmaf(patch[ij * 128 + g * 16 + m], wr[m], acc);
            u[g * 9 + ij] = acc;
        }
    }

    float v = 0.0f;
    #pragma unroll
    for (int n = 0; n < NPRI; ++n) v += u[n];
    v *= (1.0f / NPRI);
    #pragma unroll 1
    for (int it = 0; it < 3; ++it) {
        float s = dpp_add16(v * v);
        float vn = v * frcp(fmaxf(sqrtf(s), 1e-12f));
        float ssum = 0.0f, vacc = 0.0f;
        #pragma unroll
        for (int n = 0; n < NPRI; ++n) {
            float p = dpp_add16(u[n] * vn);
            float e = __expf(p);
            ssum += e;
            vacc = fmaf(e, u[n], vacc);
        }
        v = vacc * frcp(ssum);
    }
    float s = dpp_add16(v * v);
    float res = v * sqrtf(s) * frcp(1.0f + s);
    out[((b * 256 + t) * 32 + h) * 32 + w] = res;
}

extern "C" void kernel_launch(void* const* d_in, const int* in_sizes, int n_in,
                              void* d_out, int out_size, void* d_ws, size_t ws_size,
                              hipStream_t stream) {
    const float* x = (const float*)d_in[0];   // [2,128,32,32]
    const float* W = (const float*)d_in[1];   // [16,16,16,3,3]
    float* out = (float*)d_out;               // [2,256,32,32]
    float* xT = (float*)d_ws;
    float* Wt = xT + XT_ELEMS;

    const size_t need = (size_t)(XT_ELEMS + WT_ELEMS) * sizeof(float);
    if (ws_size >= need) {
        prep_kernel<<<208, 256, 0, stream>>>(x, W, xT, Wt);
        capsule_v5<<<2048, 256, 0, stream>>>(xT, Wt, out);
    } else {
        capsule_fb<<<2048, 256, 0, stream>>>(x, W, out);
    }
}

// Round 9
// 102.772 us; speedup vs baseline: 1.0435x; 1.0435x over previous
//
#include <hip/hip_runtime.h>

// CapsuleConv2d fused, MI355X gfx950. ALL I/O FP32.
// B=2, C_in=128 (G=8 x M=16), 32x32, 3x3 pad 1, O=16, L=16 -> C_out=256.
// k-means (dot) routing 3 iters + squash.
//
// v6 = v5 with phase-2 FULLY SCALARIZED (no local arrays at all).
// R7/R8 evidence: ~49 MB scratch writes persisted even at launch_bounds
// (256,1) (512-reg budget, ~190 live) -> spill was NOT pressure-driven but
// an SROA/alloca failure on the phase-2 arrays. Named registers remove the
// alloca entirely.
// Structure: 1 block/pixel; priors computed in two g-halves woven into a
// two-chunk LDS transpose (u[72] never materialized); phase 2 thread=(o,nc)
// owns 4-5 u-rows (all 16 l) in named regs; routing register-local
// (5 exps/lane/iter); v-updates via DPP 16-lane all-reduce.

typedef float v2f __attribute__((ext_vector_type(2)));

#define NPRI 72
#define XT_ELEMS (2 * 32 * 32 * 128)   // 1 MB
#define WT_ELEMS (9 * 256 * 16)        // 576 KB
#define ROWSTR 268                     // LDS row stride (floats); 16B-aligned

#define DPP_ADD(a, ctrl)                                                     \
  a += __int_as_float(__builtin_amdgcn_update_dpp(                           \
          0, __float_as_int(a), ctrl, 0xF, 0xF, true))

__device__ __forceinline__ float dpp_add16(float x) {
    // sum across each aligned 16-lane group, broadcast to all 16 lanes.
    float s = x;
    DPP_ADD(s, 0x128); DPP_ADD(s, 0x124); DPP_ADD(s, 0x122); DPP_ADD(s, 0x121);
    return s;
}

__device__ __forceinline__ float frcp(float x) {
    return __builtin_amdgcn_rcpf(x);
}

__device__ __forceinline__ v2f pkfma(v2f a, v2f b, v2f c) {
    return __builtin_elementwise_fma(a, b, c);
}

// ---- prep: blocks [0,64) x-transpose, [64,208) weight transpose ----
// xT[b][h][w][c] = x[b][c][h][w];  Wt[(ij*256+t)*16+m] = W[(t*16+m)*9+ij]
__global__ __launch_bounds__(256)
void prep_kernel(const float* __restrict__ x, const float* __restrict__ W,
                 float* __restrict__ xT, float* __restrict__ Wt) {
    const int blk = blockIdx.x;
    const int tid = threadIdx.x;
    if (blk < 64) {
        __shared__ float xs[128 * 33];
        const int b = blk >> 5, h = blk & 31;
        const float* xb = x + b * (128 * 32 * 32) + h * 32;  // [c*1024 + w]
        #pragma unroll
        for (int k = 0; k < 16; ++k) {
            int idx = k * 256 + tid;
            int c = idx >> 5, w = idx & 31;
            xs[c * 33 + w] = xb[c * 1024 + w];   // coalesced read
        }
        __syncthreads();
        float* xo = xT + (b * 32 + h) * 32 * 128;
        #pragma unroll
        for (int k = 0; k < 16; ++k) {
            int idx = k * 256 + tid;
            int w = idx >> 7, c = idx & 127;
            xo[w * 128 + c] = xs[c * 33 + w];    // coalesced write, cf-free read
        }
    } else {
        int idx = (blk - 64) * 256 + tid;        // 0..36863
        int ij = idx >> 12;
        int r  = idx & 4095;
        int tt = r >> 4;
        int m  = r & 15;
        Wt[idx] = W[(tt * 16 + m) * 9 + ij];
    }
}

// scalarized helpers ---------------------------------------------------------
#define LOAD_ROW(K, ROW)                                                     \
  do {                                                                       \
    const v2f* r2_ = (const v2f*)&uTs[(ROW) * ROWSTR + o * 16];              \
    U##K##0 = r2_[0]; U##K##1 = r2_[1]; U##K##2 = r2_[2]; U##K##3 = r2_[3];  \
    U##K##4 = r2_[4]; U##K##5 = r2_[5]; U##K##6 = r2_[6]; U##K##7 = r2_[7];  \
  } while (0)

#define DOT_ROW(K)                                                           \
  ({ v2f d_ = U##K##0 * V0;                                                  \
     d_ = pkfma(U##K##1, V1, d_); d_ = pkfma(U##K##2, V2, d_);               \
     d_ = pkfma(U##K##3, V3, d_); d_ = pkfma(U##K##4, V4, d_);               \
     d_ = pkfma(U##K##5, V5, d_); d_ = pkfma(U##K##6, V6, d_);               \
     d_ = pkfma(U##K##7, V7, d_); (d_.x + d_.y); })

#define MEAN1(J)                                                             \
  { v2f s_ = (U0##J + U1##J) + (U2##J + U3##J) + U4##J;                      \
    V##J.x = dpp_add16(s_.x) * (1.0f / NPRI);                                \
    V##J.y = dpp_add16(s_.y) * (1.0f / NPRI); }

#define UPD1(J)                                                              \
  { v2f pv_ = e0v * U0##J;                                                   \
    pv_ = pkfma(e1v, U1##J, pv_); pv_ = pkfma(e2v, U2##J, pv_);              \
    pv_ = pkfma(e3v, U3##J, pv_); pv_ = pkfma(e4v, U4##J, pv_);              \
    V##J.x = dpp_add16(pv_.x) * rs;                                          \
    V##J.y = dpp_add16(pv_.y) * rs; }

#define PRIOR_G(G, GOFF)                                                     \
  { v2f acc_ = sp2[(GOFF) * 8 + 0] * Wm0;                                    \
    acc_ = pkfma(sp2[(GOFF) * 8 + 1], Wm1, acc_);                            \
    acc_ = pkfma(sp2[(GOFF) * 8 + 2], Wm2, acc_);                            \
    acc_ = pkfma(sp2[(GOFF) * 8 + 3], Wm3, acc_);                            \
    acc_ = pkfma(sp2[(GOFF) * 8 + 4], Wm4, acc_);                            \
    acc_ = pkfma(sp2[(GOFF) * 8 + 5], Wm5, acc_);                            \
    acc_ = pkfma(sp2[(GOFF) * 8 + 6], Wm6, acc_);                            \
    acc_ = pkfma(sp2[(GOFF) * 8 + 7], Wm7, acc_);                            \
    uTs[((G) * 9 + ij) * ROWSTR + t] = acc_.x + acc_.y; }

// ---- main kernel v6 ----
__global__ __launch_bounds__(256, 2)
void capsule_v6(const float* __restrict__ xT, const float* __restrict__ Wt,
                float* __restrict__ out) {
    __shared__ float uTs[36 * ROWSTR];       // 38.6 KB, two-chunk transpose
    const int pix = blockIdx.x;              // 2048
    const int b = pix >> 10, h = (pix >> 5) & 31, w = pix & 31;
    const int t = threadIdx.x;
    const int o = t >> 4, nc = t & 15;       // phase1: l == nc

    v2f U00, U01, U02, U03, U04, U05, U06, U07;
    v2f U10, U11, U12, U13, U14, U15, U16, U17;
    v2f U20, U21, U22, U23, U24, U25, U26, U27;
    v2f U30, U31, U32, U33, U34, U35, U36, U37;
    v2f U40, U41, U42, U43, U44, U45, U46, U47;
    U40 = U41 = U42 = U43 = U44 = U45 = U46 = U47 = (v2f){0.0f, 0.0f};
    const bool has5 = (nc < 8);

    // ================= PASS A: g=0..3 -> LDS rows 0..35 =================
    #pragma unroll
    for (int ij = 0; ij < 9; ++ij) {
        const int di = ij / 3, dj = ij % 3;
        const int hh = h + di - 1, ww = w + dj - 1;
        if ((unsigned)hh < 32u && (unsigned)ww < 32u) {     // block-uniform
            const v2f* sp2 = (const v2f*)(xT + ((b * 32 + hh) * 32 + ww) * 128);
            const v2f* wp2 = (const v2f*)(Wt + (ij * 256 + t) * 16);
            v2f Wm0 = wp2[0], Wm1 = wp2[1], Wm2 = wp2[2], Wm3 = wp2[3];
            v2f Wm4 = wp2[4], Wm5 = wp2[5], Wm6 = wp2[6], Wm7 = wp2[7];
            PRIOR_G(0, 0) PRIOR_G(1, 1) PRIOR_G(2, 2) PRIOR_G(3, 3)
        } else {
            #pragma unroll
            for (int g = 0; g < 4; ++g)
                uTs[(g * 9 + ij) * ROWSTR + t] = 0.0f;
        }
    }
    __syncthreads();
    LOAD_ROW(0, nc);
    LOAD_ROW(1, 16 + nc);
    if (nc < 4) LOAD_ROW(2, 32 + nc);
    __syncthreads();

    // ================= PASS B: g=4..7 -> LDS rows 36..71 (stored -36) ====
    #pragma unroll
    for (int ij = 0; ij < 9; ++ij) {
        const int di = ij / 3, dj = ij % 3;
        const int hh = h + di - 1, ww = w + dj - 1;
        if ((unsigned)hh < 32u && (unsigned)ww < 32u) {
            const v2f* sp2 = (const v2f*)(xT + ((b * 32 + hh) * 32 + ww) * 128);
            const v2f* wp2 = (const v2f*)(Wt + (ij * 256 + t) * 16);
            v2f Wm0 = wp2[0], Wm1 = wp2[1], Wm2 = wp2[2], Wm3 = wp2[3];
            v2f Wm4 = wp2[4], Wm5 = wp2[5], Wm6 = wp2[6], Wm7 = wp2[7];
            PRIOR_G(0, 4) PRIOR_G(1, 5) PRIOR_G(2, 6) PRIOR_G(3, 7)
        } else {
            #pragma unroll
            for (int g = 0; g < 4; ++g)
                uTs[(g * 9 + ij) * ROWSTR + t] = 0.0f;
        }
    }
    __syncthreads();
    if (nc >= 4) LOAD_ROW(2, nc - 4);
    LOAD_ROW(3, 12 + nc);
    if (has5) LOAD_ROW(4, 28 + nc);

    // ---- init v = mean over n (U4x = 0 for !has5 lanes) ----
    v2f V0, V1, V2, V3, V4, V5, V6, V7;
    MEAN1(0) MEAN1(1) MEAN1(2) MEAN1(3) MEAN1(4) MEAN1(5) MEAN1(6) MEAN1(7)

    // ---- 3 routing iterations, named registers only ----
    #pragma unroll 1
    for (int it = 0; it < 3; ++it) {
        v2f ssv = V0 * V0;
        ssv = pkfma(V1, V1, ssv); ssv = pkfma(V2, V2, ssv);
        ssv = pkfma(V3, V3, ssv); ssv = pkfma(V4, V4, ssv);
        ssv = pkfma(V5, V5, ssv); ssv = pkfma(V6, V6, ssv);
        ssv = pkfma(V7, V7, ssv);
        float ss = ssv.x + ssv.y;
        float inv = frcp(fmaxf(sqrtf(ss), 1e-12f));

        float E0 = __expf(DOT_ROW(0) * inv);
        float E1 = __expf(DOT_ROW(1) * inv);
        float E2 = __expf(DOT_ROW(2) * inv);
        float E3 = __expf(DOT_ROW(3) * inv);
        float E4 = has5 ? __expf(DOT_ROW(4) * inv) : 0.0f;
        float ssum = dpp_add16(((E0 + E1) + (E2 + E3)) + E4);
        float rs = frcp(ssum);

        v2f e0v = {E0, E0}, e1v = {E1, E1}, e2v = {E2, E2};
        v2f e3v = {E3, E3}, e4v = {E4, E4};
        UPD1(0) UPD1(1) UPD1(2) UPD1(3) UPD1(4) UPD1(5) UPD1(6) UPD1(7)
    }

    // ---- squash ----
    v2f ssv = V0 * V0;
    ssv = pkfma(V1, V1, ssv); ssv = pkfma(V2, V2, ssv);
    ssv = pkfma(V3, V3, ssv); ssv = pkfma(V4, V4, ssv);
    ssv = pkfma(V5, V5, ssv); ssv = pkfma(V6, V6, ssv);
    ssv = pkfma(V7, V7, ssv);
    float ss = ssv.x + ssv.y;
    float scale = sqrtf(ss) * frcp(1.0f + ss);

    // select component l = nc via scalar cndmask ladder
    v2f a0 = (nc & 8) ? V4 : V0;
    v2f a1 = (nc & 8) ? V5 : V1;
    v2f a2 = (nc & 8) ? V6 : V2;
    v2f a3 = (nc & 8) ? V7 : V3;
    v2f b0 = (nc & 4) ? a2 : a0;
    v2f b1 = (nc & 4) ? a3 : a1;
    v2f c0 = (nc & 2) ? b1 : b0;
    float res = ((nc & 1) ? c0.y : c0.x) * scale;

    out[((b * 256 + t) * 32 + h) * 32 + w] = res;
}

// ---- fallback (tiny ws): self-contained ----
__global__ __launch_bounds__(256, 1)
void capsule_fb(const float* __restrict__ x, const float* __restrict__ Wraw,
                float* __restrict__ out) {
    __shared__ float patch[9 * 128];
    const int blk = blockIdx.x;
    const int b = blk >> 10, h = (blk >> 5) & 31, w = blk & 31;
    const int t = threadIdx.x;

    const float* xb = x + b * (128 * 32 * 32);
    for (int idx = t; idx < 1152; idx += 256) {
        int c = idx / 9, ij = idx - c * 9;
        int di = ij / 3, dj = ij - di * 3;
        int hh = h + di - 1, ww = w + dj - 1;
        float v = 0.0f;
        if ((unsigned)hh < 32u && (unsigned)ww < 32u)
            v = xb[(c * 32 + hh) * 32 + ww];
        patch[ij * 128 + c] = v;
    }
    __syncthreads();

    float u[NPRI];
    #pragma unroll
    for (int ij = 0; ij < 9; ++ij) {
        float wr[16];
        #pragma unroll
        for (int m = 0; m < 16; ++m) wr[m] = Wraw[(t * 16 + m) * 9 + ij];
        #pragma unroll
        for (int g = 0; g < 8; ++g) {
            float acc = 0.0f;
            #pragma unroll
            for (int m = 0; m < 16; ++m)
                acc = fmaf(patch[ij * 128 + g * 16 + m], wr[m], acc);
            u[g * 9 + ij] = acc;
        }
    }

    float v = 0.0f;
    #pragma unroll
    for (int n = 0; n < NPRI; ++n) v += u[n];
    v *= (1.0f / NPRI);
    #pragma unroll 1
    for (int it = 0; it < 3; ++it) {
        float s = dpp_add16(v * v);
        float vn = v * frcp(fmaxf(sqrtf(s), 1e-12f));
        float ssum = 0.0f, vacc = 0.0f;
        #pragma unroll
        for (int n = 0; n < NPRI; ++n) {
            float p = dpp_add16(u[n] * vn);
            float e = __expf(p);
            ssum += e;
            vacc = fmaf(e, u[n], vacc);
        }
        v = vacc * frcp(ssum);
    }
    float s = dpp_add16(v * v);
    float res = v * sqrtf(s) * frcp(1.0f + s);
    out[((b * 256 + t) * 32 + h) * 32 + w] = res;
}

extern "C" void kernel_launch(void* const* d_in, const int* in_sizes, int n_in,
                              void* d_out, int out_size, void* d_ws, size_t ws_size,
                              hipStream_t stream) {
    const float* x = (const float*)d_in[0];   // [2,128,32,32]
    const float* W = (const float*)d_in[1];   // [16,16,16,3,3]
    float* out = (float*)d_out;               // [2,256,32,32]
    float* xT = (float*)d_ws;
    float* Wt = xT + XT_ELEMS;

    const size_t need = (size_t)(XT_ELEMS + WT_ELEMS) * sizeof(float);
    if (ws_size >= need) {
        prep_kernel<<<208, 256, 0, stream>>>(x, W, xT, Wt);
        capsule_v6<<<2048, 256, 0, stream>>>(xT, Wt, out);
    } else {
        capsule_fb<<<2048, 256, 0, stream>>>(x, W, out);
    }
}

// Round 10
// 100.346 us; speedup vs baseline: 1.0687x; 1.0242x over previous
//
#include <hip/hip_runtime.h>

// CapsuleConv2d fused, MI355X gfx950. ALL I/O FP32.
// B=2, C_in=128 (G=8 x M=16), 32x32, 3x3 pad 1, O=16, L=16 -> C_out=256.
// k-means (dot) routing 3 iters + squash.
//
// v7 = v6 (fully scalarized phase 2 -- R9 proved this kills the non-pressure
// scratch spill) with the prior passes split by IJ instead of G:
//   pass A: ij 0..4, all 8 g  -> LDS rows ij*8+g      (40 rows)
//   pass B: ij 5..8, all 8 g  -> LDS rows (ij-5)*8+g  (32 rows)
// Each ij's 16 weights are loaded ONCE (36 dwordx4/thread vs 72 in v6 --
// v6's g-halves reloaded identical weights in both passes; ~600 MB of
// L2->CU weight traffic halved, and half the 200-cyc VMEM dependency
// chains). Phase-2 row ownership (thread (o,nc) owns n = nc+16k) is now
// runtime-mapped to chunk/row. launch_bounds(256,3): live ~130 regs < 170.

typedef float v2f __attribute__((ext_vector_type(2)));

#define NPRI 72
#define XT_ELEMS (2 * 32 * 32 * 128)   // 1 MB
#define WT_ELEMS (9 * 256 * 16)        // 576 KB
#define ROWSTR 260                     // LDS row stride (floats); 16B-aligned

#define DPP_ADD(a, ctrl)                                                     \
  a += __int_as_float(__builtin_amdgcn_update_dpp(                           \
          0, __float_as_int(a), ctrl, 0xF, 0xF, true))

__device__ __forceinline__ float dpp_add16(float x) {
    // sum across each aligned 16-lane group, broadcast to all 16 lanes.
    float s = x;
    DPP_ADD(s, 0x128); DPP_ADD(s, 0x124); DPP_ADD(s, 0x122); DPP_ADD(s, 0x121);
    return s;
}

__device__ __forceinline__ float frcp(float x) {
    return __builtin_amdgcn_rcpf(x);
}

__device__ __forceinline__ v2f pkfma(v2f a, v2f b, v2f c) {
    return __builtin_elementwise_fma(a, b, c);
}

// ---- prep: blocks [0,64) x-transpose, [64,208) weight transpose ----
// xT[b][h][w][c] = x[b][c][h][w];  Wt[(ij*256+t)*16+m] = W[(t*16+m)*9+ij]
__global__ __launch_bounds__(256)
void prep_kernel(const float* __restrict__ x, const float* __restrict__ W,
                 float* __restrict__ xT, float* __restrict__ Wt) {
    const int blk = blockIdx.x;
    const int tid = threadIdx.x;
    if (blk < 64) {
        __shared__ float xs[128 * 33];
        const int b = blk >> 5, h = blk & 31;
        const float* xb = x + b * (128 * 32 * 32) + h * 32;  // [c*1024 + w]
        #pragma unroll
        for (int k = 0; k < 16; ++k) {
            int idx = k * 256 + tid;
            int c = idx >> 5, w = idx & 31;
            xs[c * 33 + w] = xb[c * 1024 + w];   // coalesced read
        }
        __syncthreads();
        float* xo = xT + (b * 32 + h) * 32 * 128;
        #pragma unroll
        for (int k = 0; k < 16; ++k) {
            int idx = k * 256 + tid;
            int w = idx >> 7, c = idx & 127;
            xo[w * 128 + c] = xs[c * 33 + w];    // coalesced write, cf-free read
        }
    } else {
        int idx = (blk - 64) * 256 + tid;        // 0..36863
        int ij = idx >> 12;
        int r  = idx & 4095;
        int tt = r >> 4;
        int m  = r & 15;
        Wt[idx] = W[(tt * 16 + m) * 9 + ij];
    }
}

// scalarized helpers ---------------------------------------------------------
#define LOAD_ROW_IF(K, COND, ROW)                                            \
  if (COND) {                                                                \
    const v2f* r2_ = (const v2f*)&uTs[(ROW) * ROWSTR + o * 16];              \
    U##K##0 = r2_[0]; U##K##1 = r2_[1]; U##K##2 = r2_[2]; U##K##3 = r2_[3];  \
    U##K##4 = r2_[4]; U##K##5 = r2_[5]; U##K##6 = r2_[6]; U##K##7 = r2_[7];  \
  }

#define DOT_ROW(K)                                                           \
  ({ v2f d_ = U##K##0 * V0;                                                  \
     d_ = pkfma(U##K##1, V1, d_); d_ = pkfma(U##K##2, V2, d_);               \
     d_ = pkfma(U##K##3, V3, d_); d_ = pkfma(U##K##4, V4, d_);               \
     d_ = pkfma(U##K##5, V5, d_); d_ = pkfma(U##K##6, V6, d_);               \
     d_ = pkfma(U##K##7, V7, d_); (d_.x + d_.y); })

#define MEAN1(J)                                                             \
  { v2f s_ = (U0##J + U1##J) + (U2##J + U3##J) + U4##J;                      \
    V##J.x = dpp_add16(s_.x) * (1.0f / NPRI);                                \
    V##J.y = dpp_add16(s_.y) * (1.0f / NPRI); }

#define UPD1(J)                                                              \
  { v2f pv_ = e0v * U0##J;                                                   \
    pv_ = pkfma(e1v, U1##J, pv_); pv_ = pkfma(e2v, U2##J, pv_);              \
    pv_ = pkfma(e3v, U3##J, pv_); pv_ = pkfma(e4v, U4##J, pv_);              \
    V##J.x = dpp_add16(pv_.x) * rs;                                          \
    V##J.y = dpp_add16(pv_.y) * rs; }

// one prior value: g-row G of patch (sp2) dot weights Wm0..7 -> LDS row
#define PRIOR_G(G, IJROW)                                                    \
  { v2f acc_ = sp2[(G) * 8 + 0] * Wm0;                                       \
    acc_ = pkfma(sp2[(G) * 8 + 1], Wm1, acc_);                               \
    acc_ = pkfma(sp2[(G) * 8 + 2], Wm2, acc_);                               \
    acc_ = pkfma(sp2[(G) * 8 + 3], Wm3, acc_);                               \
    acc_ = pkfma(sp2[(G) * 8 + 4], Wm4, acc_);                               \
    acc_ = pkfma(sp2[(G) * 8 + 5], Wm5, acc_);                               \
    acc_ = pkfma(sp2[(G) * 8 + 6], Wm6, acc_);                               \
    acc_ = pkfma(sp2[(G) * 8 + 7], Wm7, acc_);                               \
    uTs[((IJROW) * 8 + (G)) * ROWSTR + t] = acc_.x + acc_.y; }

#define PRIOR_IJ(IJ, IJROW)                                                  \
  { const int di = (IJ) / 3, dj = (IJ) % 3;                                  \
    const int hh = h + di - 1, ww = w + dj - 1;                              \
    if ((unsigned)hh < 32u && (unsigned)ww < 32u) {                          \
        const v2f* sp2 = (const v2f*)(xT + ((b * 32 + hh) * 32 + ww) * 128); \
        const v2f* wp2 = (const v2f*)(Wt + ((IJ) * 256 + t) * 16);           \
        v2f Wm0 = wp2[0], Wm1 = wp2[1], Wm2 = wp2[2], Wm3 = wp2[3];          \
        v2f Wm4 = wp2[4], Wm5 = wp2[5], Wm6 = wp2[6], Wm7 = wp2[7];          \
        PRIOR_G(0, IJROW) PRIOR_G(1, IJROW) PRIOR_G(2, IJROW)                \
        PRIOR_G(3, IJROW) PRIOR_G(4, IJROW) PRIOR_G(5, IJROW)                \
        PRIOR_G(6, IJROW) PRIOR_G(7, IJROW)                                  \
    } else {                                                                 \
        _Pragma("unroll")                                                    \
        for (int g_ = 0; g_ < 8; ++g_)                                       \
            uTs[((IJROW) * 8 + g_) * ROWSTR + t] = 0.0f;                     \
    } }

// ---- main kernel v7 ----
__global__ __launch_bounds__(256, 3)
void capsule_v7(const float* __restrict__ xT, const float* __restrict__ Wt,
                float* __restrict__ out) {
    __shared__ float uTs[40 * ROWSTR];       // 41.6 KB (pass A: 40 rows)
    const int pix = blockIdx.x;              // 2048
    const int b = pix >> 10, h = (pix >> 5) & 31, w = pix & 31;
    const int t = threadIdx.x;
    const int o = t >> 4, nc = t & 15;       // phase1: l == nc

    v2f U00, U01, U02, U03, U04, U05, U06, U07;
    v2f U10, U11, U12, U13, U14, U15, U16, U17;
    v2f U20, U21, U22, U23, U24, U25, U26, U27;
    v2f U30, U31, U32, U33, U34, U35, U36, U37;
    v2f U40, U41, U42, U43, U44, U45, U46, U47;
    U40 = U41 = U42 = U43 = U44 = U45 = U46 = U47 = (v2f){0.0f, 0.0f};
    const bool has5 = (nc < 8);

    // phase-2 row ownership: n = nc+16k -> g=n/9, ij=n%9
    // ij<5 -> chunk A row ij*8+g ; ij>=5 -> chunk B row (ij-5)*8+g
    int n0 = nc,      g0 = n0 / 9, ij0 = n0 % 9;
    int n1 = nc + 16, g1 = n1 / 9, ij1 = n1 % 9;
    int n2 = nc + 32, g2 = n2 / 9, ij2 = n2 % 9;
    int n3 = nc + 48, g3 = n3 / 9, ij3 = n3 % 9;
    int n4 = nc + 64, g4 = n4 / 9, ij4 = n4 % 9;
    const bool inA0 = ij0 < 5, inA1 = ij1 < 5, inA2 = ij2 < 5;
    const bool inA3 = ij3 < 5, inA4 = ij4 < 5;
    const int row0 = inA0 ? (ij0 * 8 + g0) : ((ij0 - 5) * 8 + g0);
    const int row1 = inA1 ? (ij1 * 8 + g1) : ((ij1 - 5) * 8 + g1);
    const int row2 = inA2 ? (ij2 * 8 + g2) : ((ij2 - 5) * 8 + g2);
    const int row3 = inA3 ? (ij3 * 8 + g3) : ((ij3 - 5) * 8 + g3);
    const int row4 = inA4 ? (ij4 * 8 + g4) : ((ij4 - 5) * 8 + g4);

    // ================= PASS A: ij 0..4 -> rows ij*8+g =================
    PRIOR_IJ(0, 0) PRIOR_IJ(1, 1) PRIOR_IJ(2, 2) PRIOR_IJ(3, 3) PRIOR_IJ(4, 4)
    __syncthreads();
    LOAD_ROW_IF(0, inA0, row0)
    LOAD_ROW_IF(1, inA1, row1)
    LOAD_ROW_IF(2, inA2, row2)
    LOAD_ROW_IF(3, inA3, row3)
    LOAD_ROW_IF(4, inA4 && has5, row4)
    __syncthreads();

    // ================= PASS B: ij 5..8 -> rows (ij-5)*8+g =============
    PRIOR_IJ(5, 0) PRIOR_IJ(6, 1) PRIOR_IJ(7, 2) PRIOR_IJ(8, 3)
    __syncthreads();
    LOAD_ROW_IF(0, !inA0, row0)
    LOAD_ROW_IF(1, !inA1, row1)
    LOAD_ROW_IF(2, !inA2, row2)
    LOAD_ROW_IF(3, !inA3, row3)
    LOAD_ROW_IF(4, !inA4 && has5, row4)

    // ---- init v = mean over n (U4x = 0 for !has5 lanes) ----
    v2f V0, V1, V2, V3, V4, V5, V6, V7;
    MEAN1(0) MEAN1(1) MEAN1(2) MEAN1(3) MEAN1(4) MEAN1(5) MEAN1(6) MEAN1(7)

    // ---- 3 routing iterations, named registers only ----
    #pragma unroll 1
    for (int it = 0; it < 3; ++it) {
        v2f ssv = V0 * V0;
        ssv = pkfma(V1, V1, ssv); ssv = pkfma(V2, V2, ssv);
        ssv = pkfma(V3, V3, ssv); ssv = pkfma(V4, V4, ssv);
        ssv = pkfma(V5, V5, ssv); ssv = pkfma(V6, V6, ssv);
        ssv = pkfma(V7, V7, ssv);
        float ss = ssv.x + ssv.y;
        float inv = frcp(fmaxf(sqrtf(ss), 1e-12f));

        float E0 = __expf(DOT_ROW(0) * inv);
        float E1 = __expf(DOT_ROW(1) * inv);
        float E2 = __expf(DOT_ROW(2) * inv);
        float E3 = __expf(DOT_ROW(3) * inv);
        float E4 = has5 ? __expf(DOT_ROW(4) * inv) : 0.0f;
        float ssum = dpp_add16(((E0 + E1) + (E2 + E3)) + E4);
        float rs = frcp(ssum);

        v2f e0v = {E0, E0}, e1v = {E1, E1}, e2v = {E2, E2};
        v2f e3v = {E3, E3}, e4v = {E4, E4};
        UPD1(0) UPD1(1) UPD1(2) UPD1(3) UPD1(4) UPD1(5) UPD1(6) UPD1(7)
    }

    // ---- squash ----
    v2f ssv = V0 * V0;
    ssv = pkfma(V1, V1, ssv); ssv = pkfma(V2, V2, ssv);
    ssv = pkfma(V3, V3, ssv); ssv = pkfma(V4, V4, ssv);
    ssv = pkfma(V5, V5, ssv); ssv = pkfma(V6, V6, ssv);
    ssv = pkfma(V7, V7, ssv);
    float ss = ssv.x + ssv.y;
    float scale = sqrtf(ss) * frcp(1.0f + ss);

    // select component l = nc via scalar cndmask ladder
    v2f a0 = (nc & 8) ? V4 : V0;
    v2f a1 = (nc & 8) ? V5 : V1;
    v2f a2 = (nc & 8) ? V6 : V2;
    v2f a3 = (nc & 8) ? V7 : V3;
    v2f b0 = (nc & 4) ? a2 : a0;
    v2f b1 = (nc & 4) ? a3 : a1;
    v2f c0 = (nc & 2) ? b1 : b0;
    float res = ((nc & 1) ? c0.y : c0.x) * scale;

    out[((b * 256 + t) * 32 + h) * 32 + w] = res;
}

// ---- fallback (tiny ws): self-contained ----
__global__ __launch_bounds__(256, 1)
void capsule_fb(const float* __restrict__ x, const float* __restrict__ Wraw,
                float* __restrict__ out) {
    __shared__ float patch[9 * 128];
    const int blk = blockIdx.x;
    const int b = blk >> 10, h = (blk >> 5) & 31, w = blk & 31;
    const int t = threadIdx.x;

    const float* xb = x + b * (128 * 32 * 32);
    for (int idx = t; idx < 1152; idx += 256) {
        int c = idx / 9, ij = idx - c * 9;
        int di = ij / 3, dj = ij - di * 3;
        int hh = h + di - 1, ww = w + dj - 1;
        float v = 0.0f;
        if ((unsigned)hh < 32u && (unsigned)ww < 32u)
            v = xb[(c * 32 + hh) * 32 + ww];
        patch[ij * 128 + c] = v;
    }
    __syncthreads();

    float u[NPRI];
    #pragma unroll
    for (int ij = 0; ij < 9; ++ij) {
        float wr[16];
        #pragma unroll
        for (int m = 0; m < 16; ++m) wr[m] = Wraw[(t * 16 + m) * 9 + ij];
        #pragma unroll
        for (int g = 0; g < 8; ++g) {
            float acc = 0.0f;
            #pragma unroll
            for (int m = 0; m < 16; ++m)
                acc = fmaf(patch[ij * 128 + g * 16 + m], wr[m], acc);
            u[g * 9 + ij] = acc;
        }
    }

    float v = 0.0f;
    #pragma unroll
    for (int n = 0; n < NPRI; ++n) v += u[n];
    v *= (1.0f / NPRI);
    #pragma unroll 1
    for (int it = 0; it < 3; ++it) {
        float s = dpp_add16(v * v);
        float vn = v * frcp(fmaxf(sqrtf(s), 1e-12f));
        float ssum = 0.0f, vacc = 0.0f;
        #pragma unroll
        for (int n = 0; n < NPRI; ++n) {
            float p = dpp_add16(u[n] * vn);
            float e = __expf(p);
            ssum += e;
            vacc = fmaf(e, u[n], vacc);
        }
        v = vacc * frcp(ssum);
    }
    float s = dpp_add16(v * v);
    float res = v * sqrtf(s) * frcp(1.0f + s);
    out[((b * 256 + t) * 32 + h) * 32 + w] = res;
}

extern "C" void kernel_launch(void* const* d_in, const int* in_sizes, int n_in,
                              void* d_out, int out_size, void* d_ws, size_t ws_size,
                              hipStream_t stream) {
    const float* x = (const float*)d_in[0];   // [2,128,32,32]
    const float* W = (const float*)d_in[1];   // [16,16,16,3,3]
    float* out = (float*)d_out;               // [2,256,32,32]
    float* xT = (float*)d_ws;
    float* Wt = xT + XT_ELEMS;

    const size_t need = (size_t)(XT_ELEMS + WT_ELEMS) * sizeof(float);
    if (ws_size >= need) {
        prep_kernel<<<208, 256, 0, stream>>>(x, W, xT, Wt);
        capsule_v7<<<2048, 256, 0, stream>>>(xT, Wt, out);
    } else {
        capsule_fb<<<2048, 256, 0, stream>>>(x, W, out);
    }
}